// Round 1
// baseline (94.171 us; speedup 1.0000x reference)
//
#include <hip/hip_runtime.h>
#include <math.h>

#define NPTS 2048
#define QQ 8
#define LAT 64
#define LOG2E 1.4426950408889634f
#define TWOPI 6.283185307179586f

// Feature buffer layout (per side): [4 feats][QQ][n]
//   feat 0: a   = w * 2^(1/4) * sqrt(s)
//   feat 1: s2  = s*s
//   feat 2: c   = cos(2*pi*phase)
//   feat 3: sn  = sin(2*pi*phase)
#define FSTRIDE (QQ * NPTS)

__device__ __forceinline__ float softplus_f(float v) {
    return fmaxf(v, 0.f) + log1pf(expf(-fabsf(v)));
}

__global__ __launch_bounds__(256) void feat_kernel(
    const float* __restrict__ P, int n,
    const float* __restrict__ W1, const float* __restrict__ b1,
    const float* __restrict__ Ww, const float* __restrict__ bw,
    const float* __restrict__ Wf, const float* __restrict__ bf,
    const float* __restrict__ Ws, const float* __restrict__ bs,
    float* __restrict__ F)
{
    int i = blockIdx.x * 256 + threadIdx.x;
    if (i >= n) return;
    float p0 = P[i*3+0], p1 = P[i*3+1], p2 = P[i*3+2];

    float h[LAT];
    const float lam = 1.0507009873554805f, alf = 1.6732632423543772f;
    #pragma unroll
    for (int l = 0; l < LAT; ++l) {
        float v = fmaf(W1[l*3+0], p0, fmaf(W1[l*3+1], p1, fmaf(W1[l*3+2], p2, b1[l])));
        h[l] = v > 0.f ? lam * v : lam * alf * (expf(v) - 1.f);
    }

    for (int q = 0; q < QQ; ++q) {
        float w  = bw[q];
        float s  = bs[q];
        float f0 = bf[q*3+0], f1 = bf[q*3+1], f2 = bf[q*3+2];
        #pragma unroll
        for (int l = 0; l < LAT; ++l) {
            float hv = h[l];
            w  = fmaf(Ww[q*LAT + l],       hv, w);
            s  = fmaf(Ws[q*LAT + l],       hv, s);
            f0 = fmaf(Wf[(q*3+0)*LAT + l], hv, f0);
            f1 = fmaf(Wf[(q*3+1)*LAT + l], hv, f1);
            f2 = fmaf(Wf[(q*3+2)*LAT + l], hv, f2);
        }
        w  = softplus_f(w);
        s  = softplus_f(s);
        f0 = softplus_f(f0);
        f1 = softplus_f(f1);
        f2 = softplus_f(f2);
        float phase = f0*p0 + f1*p1 + f2*p2;
        float ang = TWOPI * phase;
        F[0*FSTRIDE + q*n + i] = w * 1.1892071150027210f * sqrtf(s);
        F[1*FSTRIDE + q*n + i] = s * s;
        F[2*FSTRIDE + q*n + i] = cosf(ang);
        F[3*FSTRIDE + q*n + i] = sinf(ang);
    }
}

__global__ __launch_bounds__(256) void pair_kernel(
    const float* __restrict__ x, const float* __restrict__ y,
    const float* __restrict__ FX, const float* __restrict__ FY,
    float* __restrict__ K)
{
    __shared__ float lf[2][4][QQ][64];   // [side][feat][q][pt] = 16 KiB
    __shared__ float lp[2][3][64];       // positions, 1.5 KiB

    const int t  = threadIdx.x;
    const int tx = t & 15, ty = t >> 4;
    const int i0 = blockIdx.y * 64, j0 = blockIdx.x * 64;

    // Stage features: each (feat,k) pass loads 512 contiguous-by-row floats.
    #pragma unroll
    for (int f = 0; f < 4; ++f) {
        #pragma unroll
        for (int k = 0; k < 2; ++k) {
            int idx = t + k * 256;          // 0..511
            int q = idx >> 6, ii = idx & 63;
            lf[0][f][q][ii] = FX[f*FSTRIDE + q*NPTS + i0 + ii];
            lf[1][f][q][ii] = FY[f*FSTRIDE + q*NPTS + j0 + ii];
        }
    }
    if (t < 192) {
        int d = t >> 6, ii = t & 63;
        lp[0][d][ii] = x[(i0 + ii)*3 + d];
        lp[1][d][ii] = y[(j0 + ii)*3 + d];
    }
    __syncthreads();

    // d2n[ii][jj] = -log2(e) * ||x_i - y_j||^2
    float d2n[4][4];
    #pragma unroll
    for (int ii = 0; ii < 4; ++ii) {
        float xi0 = lp[0][0][ty*4+ii];
        float xi1 = lp[0][1][ty*4+ii];
        float xi2 = lp[0][2][ty*4+ii];
        #pragma unroll
        for (int jj = 0; jj < 4; ++jj) {
            float dx = xi0 - lp[1][0][tx*4+jj];
            float dy = xi1 - lp[1][1][tx*4+jj];
            float dz = xi2 - lp[1][2][tx*4+jj];
            d2n[ii][jj] = -LOG2E * fmaf(dx, dx, fmaf(dy, dy, dz*dz));
        }
    }

    float acc[4][4] = {};
    #pragma unroll
    for (int q = 0; q < QQ; ++q) {
        float4 aiv  = *(const float4*)&lf[0][0][q][ty*4];
        float4 s2iv = *(const float4*)&lf[0][1][q][ty*4];
        float4 civ  = *(const float4*)&lf[0][2][q][ty*4];
        float4 siv  = *(const float4*)&lf[0][3][q][ty*4];
        float4 ajv  = *(const float4*)&lf[1][0][q][tx*4];
        float4 s2jv = *(const float4*)&lf[1][1][q][tx*4];
        float4 cjv  = *(const float4*)&lf[1][2][q][tx*4];
        float4 sjv  = *(const float4*)&lf[1][3][q][tx*4];
        float ai[4]  = {aiv.x,  aiv.y,  aiv.z,  aiv.w};
        float s2i[4] = {s2iv.x, s2iv.y, s2iv.z, s2iv.w};
        float ci[4]  = {civ.x,  civ.y,  civ.z,  civ.w};
        float si[4]  = {siv.x,  siv.y,  siv.z,  siv.w};
        float aj[4]  = {ajv.x,  ajv.y,  ajv.z,  ajv.w};
        float s2j[4] = {s2jv.x, s2jv.y, s2jv.z, s2jv.w};
        float cj[4]  = {cjv.x,  cjv.y,  cjv.z,  cjv.w};
        float sj[4]  = {sjv.x,  sjv.y,  sjv.z,  sjv.w};
        #pragma unroll
        for (int ii = 0; ii < 4; ++ii) {
            #pragma unroll
            for (int jj = 0; jj < 4; ++jj) {
                float s2  = s2i[ii] + s2j[jj];
                float inv = __builtin_amdgcn_rcpf(s2);
                float e   = __builtin_amdgcn_exp2f(d2n[ii][jj] * inv);
                float ct  = fmaf(ci[ii], cj[jj], si[ii] * sj[jj]);
                float amp = (ai[ii] * aj[jj]) * inv;
                acc[ii][jj] = fmaf(amp, e * ct, acc[ii][jj]);
            }
        }
    }

    #pragma unroll
    for (int ii = 0; ii < 4; ++ii) {
        int i = i0 + ty*4 + ii;
        float4 o = make_float4(acc[ii][0], acc[ii][1], acc[ii][2], acc[ii][3]);
        *(float4*)&K[(size_t)i * NPTS + j0 + tx*4] = o;
    }
}

extern "C" void kernel_launch(void* const* d_in, const int* in_sizes, int n_in,
                              void* d_out, int out_size, void* d_ws, size_t ws_size,
                              hipStream_t stream) {
    const float* x  = (const float*)d_in[0];
    const float* y  = (const float*)d_in[1];
    const float* W1 = (const float*)d_in[2];
    const float* b1 = (const float*)d_in[3];
    const float* Ww = (const float*)d_in[4];
    const float* bw = (const float*)d_in[5];
    const float* Wf = (const float*)d_in[6];
    const float* bf = (const float*)d_in[7];
    const float* Ws = (const float*)d_in[8];
    const float* bs = (const float*)d_in[9];
    float* K = (float*)d_out;

    float* FX = (float*)d_ws;                      // 4*8*2048 floats = 256 KiB
    float* FY = FX + 4 * FSTRIDE;                  // another 256 KiB

    feat_kernel<<<NPTS/256, 256, 0, stream>>>(x, NPTS, W1, b1, Ww, bw, Wf, bf, Ws, bs, FX);
    feat_kernel<<<NPTS/256, 256, 0, stream>>>(y, NPTS, W1, b1, Ww, bw, Wf, bf, Ws, bs, FY);

    dim3 grid(NPTS/64, NPTS/64);
    pair_kernel<<<grid, 256, 0, stream>>>(x, y, FX, FY, K);
}

// Round 2
// 30.364 us; speedup vs baseline: 3.1014x; 3.1014x over previous
//
#include <hip/hip_runtime.h>
#include <math.h>

#define NPTS 2048
#define QQ 8
#define LAT 64
#define LOG2E 1.4426950408889634f
#define LN2 0.6931471805599453f
#define TWOPI 6.283185307179586f

// Feature buffer layout (per side): [4 feats][QQ][n]
//   feat 0: a   = w * 2^(1/4) * sqrt(s)
//   feat 1: s2  = s*s
//   feat 2: c   = cos(2*pi*phase)
//   feat 3: sn  = sin(2*pi*phase)
#define FSTRIDE (QQ * NPTS)

__device__ __forceinline__ float exp2_fast(float v) { return __builtin_amdgcn_exp2f(v); }
__device__ __forceinline__ float log2_fast(float v) { return __builtin_amdgcn_logf(v); }

__device__ __forceinline__ float softplus_f(float v) {
    // log1p(exp(v)) = max(v,0) + ln2 * log2(1 + 2^(-|v|*log2e))
    return fmaxf(v, 0.f) + LN2 * log2_fast(1.f + exp2_fast(-fabsf(v) * LOG2E));
}

// One thread per (point, q). Both sides in one launch.
// Block: 256 threads = 32 points x 8 q.  q = tid>>5, pi = tid&31.
// Grid: 128 blocks (0..63 -> x, 64..127 -> y).
__global__ __launch_bounds__(256) void feat_kernel(
    const float* __restrict__ x, const float* __restrict__ y,
    const float* __restrict__ W1, const float* __restrict__ b1,
    const float* __restrict__ Ww, const float* __restrict__ bw,
    const float* __restrict__ Wf, const float* __restrict__ bf,
    const float* __restrict__ Ws, const float* __restrict__ bs,
    float* __restrict__ FX, float* __restrict__ FY)
{
    __shared__ float4 lw1[LAT];      // W1 row + b1, 1 KiB
    __shared__ float  hw[LAT][40];   // [l][head*8 + q], 10 KiB

    const int t = threadIdx.x;
    if (t < LAT) lw1[t] = make_float4(W1[t*3+0], W1[t*3+1], W1[t*3+2], b1[t]);
    #pragma unroll
    for (int j = 0; j < 2; ++j) { int e = t + j*256; int q = e>>6, l = e&63; hw[l][q]     = Ww[e]; }
    #pragma unroll
    for (int j = 0; j < 2; ++j) { int e = t + j*256; int q = e>>6, l = e&63; hw[l][8+q]   = Ws[e]; }
    #pragma unroll
    for (int j = 0; j < 6; ++j) {
        int e = t + j*256; int r = e>>6, l = e&63;
        int q = r/3, d = r - 3*q;
        hw[l][(2+d)*8 + q] = Wf[e];
    }
    __syncthreads();

    const int side = blockIdx.x >> 6;                      // 0: x, 1: y
    const int i = ((blockIdx.x & 63) << 5) + (t & 31);     // point index
    const int q = t >> 5;
    const float* P = side ? y : x;
    float* F = side ? FY : FX;

    const float p0 = P[i*3+0], p1 = P[i*3+1], p2 = P[i*3+2];
    float w  = bw[q],     s  = bs[q];
    float f0 = bf[q*3+0], f1 = bf[q*3+1], f2 = bf[q*3+2];
    const float lam = 1.0507009873554805f, lamalf = 1.7580993408473766f;

    #pragma unroll
    for (int l = 0; l < LAT; ++l) {
        float4 wr = lw1[l];
        float v = fmaf(wr.x, p0, fmaf(wr.y, p1, fmaf(wr.z, p2, wr.w)));
        float e = exp2_fast(v * LOG2E);
        float h = v > 0.f ? lam * v : lamalf * (e - 1.f);
        w  = fmaf(hw[l][q],      h, w);
        s  = fmaf(hw[l][8+q],    h, s);
        f0 = fmaf(hw[l][16+q],   h, f0);
        f1 = fmaf(hw[l][24+q],   h, f1);
        f2 = fmaf(hw[l][32+q],   h, f2);
    }
    w  = softplus_f(w);
    s  = softplus_f(s);
    f0 = softplus_f(f0);
    f1 = softplus_f(f1);
    f2 = softplus_f(f2);
    float phase = f0*p0 + f1*p1 + f2*p2;
    float sn, cs;
    sincosf(TWOPI * phase, &sn, &cs);
    F[0*FSTRIDE + q*NPTS + i] = w * 1.1892071150027210f * sqrtf(s);
    F[1*FSTRIDE + q*NPTS + i] = s * s;
    F[2*FSTRIDE + q*NPTS + i] = cs;
    F[3*FSTRIDE + q*NPTS + i] = sn;
}

__global__ __launch_bounds__(256) void pair_kernel(
    const float* __restrict__ x, const float* __restrict__ y,
    const float* __restrict__ FX, const float* __restrict__ FY,
    float* __restrict__ K)
{
    __shared__ float lf[2][4][QQ][64];   // [side][feat][q][pt] = 16 KiB
    __shared__ float lp[2][3][64];       // positions, 1.5 KiB

    const int t  = threadIdx.x;
    const int tx = t & 15, ty = t >> 4;
    const int i0 = blockIdx.y * 64, j0 = blockIdx.x * 64;

    #pragma unroll
    for (int f = 0; f < 4; ++f) {
        #pragma unroll
        for (int k = 0; k < 2; ++k) {
            int idx = t + k * 256;          // 0..511
            int q = idx >> 6, ii = idx & 63;
            lf[0][f][q][ii] = FX[f*FSTRIDE + q*NPTS + i0 + ii];
            lf[1][f][q][ii] = FY[f*FSTRIDE + q*NPTS + j0 + ii];
        }
    }
    if (t < 192) {
        int d = t >> 6, ii = t & 63;
        lp[0][d][ii] = x[(i0 + ii)*3 + d];
        lp[1][d][ii] = y[(j0 + ii)*3 + d];
    }
    __syncthreads();

    // d2n[ii][jj] = -log2(e) * ||x_i - y_j||^2
    float d2n[4][4];
    #pragma unroll
    for (int ii = 0; ii < 4; ++ii) {
        float xi0 = lp[0][0][ty*4+ii];
        float xi1 = lp[0][1][ty*4+ii];
        float xi2 = lp[0][2][ty*4+ii];
        #pragma unroll
        for (int jj = 0; jj < 4; ++jj) {
            float dx = xi0 - lp[1][0][tx*4+jj];
            float dy = xi1 - lp[1][1][tx*4+jj];
            float dz = xi2 - lp[1][2][tx*4+jj];
            d2n[ii][jj] = -LOG2E * fmaf(dx, dx, fmaf(dy, dy, dz*dz));
        }
    }

    float acc[4][4] = {};
    #pragma unroll
    for (int q = 0; q < QQ; ++q) {
        float4 aiv  = *(const float4*)&lf[0][0][q][ty*4];
        float4 s2iv = *(const float4*)&lf[0][1][q][ty*4];
        float4 civ  = *(const float4*)&lf[0][2][q][ty*4];
        float4 siv  = *(const float4*)&lf[0][3][q][ty*4];
        float4 ajv  = *(const float4*)&lf[1][0][q][tx*4];
        float4 s2jv = *(const float4*)&lf[1][1][q][tx*4];
        float4 cjv  = *(const float4*)&lf[1][2][q][tx*4];
        float4 sjv  = *(const float4*)&lf[1][3][q][tx*4];
        float ai[4]  = {aiv.x,  aiv.y,  aiv.z,  aiv.w};
        float s2i[4] = {s2iv.x, s2iv.y, s2iv.z, s2iv.w};
        float ci[4]  = {civ.x,  civ.y,  civ.z,  civ.w};
        float si[4]  = {siv.x,  siv.y,  siv.z,  siv.w};
        float aj[4]  = {ajv.x,  ajv.y,  ajv.z,  ajv.w};
        float s2j[4] = {s2jv.x, s2jv.y, s2jv.z, s2jv.w};
        float cj[4]  = {cjv.x,  cjv.y,  cjv.z,  cjv.w};
        float sj[4]  = {sjv.x,  sjv.y,  sjv.z,  sjv.w};
        #pragma unroll
        for (int ii = 0; ii < 4; ++ii) {
            #pragma unroll
            for (int jj = 0; jj < 4; ++jj) {
                float s2  = s2i[ii] + s2j[jj];
                float inv = __builtin_amdgcn_rcpf(s2);
                float e   = __builtin_amdgcn_exp2f(d2n[ii][jj] * inv);
                float ct  = fmaf(ci[ii], cj[jj], si[ii] * sj[jj]);
                float amp = (ai[ii] * aj[jj]) * inv;
                acc[ii][jj] = fmaf(amp, e * ct, acc[ii][jj]);
            }
        }
    }

    #pragma unroll
    for (int ii = 0; ii < 4; ++ii) {
        int i = i0 + ty*4 + ii;
        float4 o = make_float4(acc[ii][0], acc[ii][1], acc[ii][2], acc[ii][3]);
        *(float4*)&K[(size_t)i * NPTS + j0 + tx*4] = o;
    }
}

extern "C" void kernel_launch(void* const* d_in, const int* in_sizes, int n_in,
                              void* d_out, int out_size, void* d_ws, size_t ws_size,
                              hipStream_t stream) {
    const float* x  = (const float*)d_in[0];
    const float* y  = (const float*)d_in[1];
    const float* W1 = (const float*)d_in[2];
    const float* b1 = (const float*)d_in[3];
    const float* Ww = (const float*)d_in[4];
    const float* bw = (const float*)d_in[5];
    const float* Wf = (const float*)d_in[6];
    const float* bf = (const float*)d_in[7];
    const float* Ws = (const float*)d_in[8];
    const float* bs = (const float*)d_in[9];
    float* K = (float*)d_out;

    float* FX = (float*)d_ws;                      // 4*8*2048 floats = 256 KiB
    float* FY = FX + 4 * FSTRIDE;                  // another 256 KiB

    feat_kernel<<<128, 256, 0, stream>>>(x, y, W1, b1, Ww, bw, Wf, bf, Ws, bs, FX, FY);

    dim3 grid(NPTS/64, NPTS/64);
    pair_kernel<<<grid, 256, 0, stream>>>(x, y, FX, FY, K);
}

// Round 3
// 27.009 us; speedup vs baseline: 3.4866x; 1.1242x over previous
//
#include <hip/hip_runtime.h>
#include <math.h>

#define NPTS 2048
#define QQ 8
#define LAT 64
#define LOG2E 1.4426950408889634f
#define SQRT_LOG2E 1.2011224087864498f
#define LN2 0.6931471805599453f

// Feature buffer layout (per side): [3 feats][QQ][n]
//   feat 0: ca = a * cos(2*pi*phase)     where a = w * 2^(1/4) * sqrt(s)
//   feat 1: sa = a * sin(2*pi*phase)
//   feat 2: s2 = s*s
#define FSTRIDE (QQ * NPTS)

__device__ __forceinline__ float exp2_fast(float v) { return __builtin_amdgcn_exp2f(v); }
__device__ __forceinline__ float log2_fast(float v) { return __builtin_amdgcn_logf(v); }

__device__ __forceinline__ float softplus_f(float v) {
    // log1p(exp(v)) = max(v,0) + ln2 * log2(1 + 2^(-|v|*log2e))
    return fmaxf(v, 0.f) + LN2 * log2_fast(1.f + exp2_fast(-fabsf(v) * LOG2E));
}

// One thread per (point, q). Both sides in one launch.
// Block: 256 threads = 32 points x 8 q.  q = tid>>5, pi = tid&31.
// Grid: 128 blocks (0..63 -> x, 64..127 -> y).
__global__ __launch_bounds__(256) void feat_kernel(
    const float* __restrict__ x, const float* __restrict__ y,
    const float* __restrict__ W1, const float* __restrict__ b1,
    const float* __restrict__ Ww, const float* __restrict__ bw,
    const float* __restrict__ Wf, const float* __restrict__ bf,
    const float* __restrict__ Ws, const float* __restrict__ bs,
    float* __restrict__ FX, float* __restrict__ FY)
{
    __shared__ float4 lw1[LAT];      // W1 row + b1, 1 KiB
    __shared__ float  hw[LAT][40];   // [l][head*8 + q], 10 KiB

    const int t = threadIdx.x;
    if (t < LAT) lw1[t] = make_float4(W1[t*3+0], W1[t*3+1], W1[t*3+2], b1[t]);
    #pragma unroll
    for (int j = 0; j < 2; ++j) { int e = t + j*256; int q = e>>6, l = e&63; hw[l][q]     = Ww[e]; }
    #pragma unroll
    for (int j = 0; j < 2; ++j) { int e = t + j*256; int q = e>>6, l = e&63; hw[l][8+q]   = Ws[e]; }
    #pragma unroll
    for (int j = 0; j < 6; ++j) {
        int e = t + j*256; int r = e>>6, l = e&63;
        int q = r/3, d = r - 3*q;
        hw[l][(2+d)*8 + q] = Wf[e];
    }
    __syncthreads();

    const int side = blockIdx.x >> 6;                      // 0: x, 1: y
    const int i = ((blockIdx.x & 63) << 5) + (t & 31);     // point index
    const int q = t >> 5;
    const float* P = side ? y : x;
    float* F = side ? FY : FX;

    const float p0 = P[i*3+0], p1 = P[i*3+1], p2 = P[i*3+2];
    float w  = bw[q],     s  = bs[q];
    float f0 = bf[q*3+0], f1 = bf[q*3+1], f2 = bf[q*3+2];
    const float lam = 1.0507009873554805f, lamalf = 1.7580993408473766f;

    #pragma unroll
    for (int l = 0; l < LAT; ++l) {
        float4 wr = lw1[l];
        float v = fmaf(wr.x, p0, fmaf(wr.y, p1, fmaf(wr.z, p2, wr.w)));
        float e = exp2_fast(v * LOG2E);
        float h = v > 0.f ? lam * v : lamalf * (e - 1.f);
        w  = fmaf(hw[l][q],      h, w);
        s  = fmaf(hw[l][8+q],    h, s);
        f0 = fmaf(hw[l][16+q],   h, f0);
        f1 = fmaf(hw[l][24+q],   h, f1);
        f2 = fmaf(hw[l][32+q],   h, f2);
    }
    w  = softplus_f(w);
    s  = softplus_f(s);
    f0 = softplus_f(f0);
    f1 = softplus_f(f1);
    f2 = softplus_f(f2);
    float phase = f0*p0 + f1*p1 + f2*p2;
    // sin(2*pi*phase) via HW sin (operates in revolutions): exact after fract.
    float fr = phase - floorf(phase);
    float sn = __builtin_amdgcn_sinf(fr);
    float cs = __builtin_amdgcn_cosf(fr);
    float a  = w * 1.1892071150027210f * sqrtf(s);
    F[0*FSTRIDE + q*NPTS + i] = a * cs;
    F[1*FSTRIDE + q*NPTS + i] = a * sn;
    F[2*FSTRIDE + q*NPTS + i] = s * s;
}

__global__ __launch_bounds__(256) void pair_kernel(
    const float* __restrict__ x, const float* __restrict__ y,
    const float* __restrict__ FX, const float* __restrict__ FY,
    float* __restrict__ K)
{
    __shared__ float lf[2][3][QQ][64];   // [side][feat][q][pt] = 12 KiB
    __shared__ float lp[2][3][64];       // positions (pre-scaled), 1.5 KiB

    const int t  = threadIdx.x;
    const int tx = t & 15, ty = t >> 4;
    const int i0 = blockIdx.y * 64, j0 = blockIdx.x * 64;

    // Stage 3 feats x 2 sides x 512 floats = 6 elems/thread.
    #pragma unroll
    for (int k = 0; k < 6; ++k) {
        int idx = t + k * 256;               // 0..1535
        int f = idx >> 9, q = (idx >> 6) & 7, ii = idx & 63;
        lf[0][f][q][ii] = FX[f*FSTRIDE + q*NPTS + i0 + ii];
        lf[1][f][q][ii] = FY[f*FSTRIDE + q*NPTS + j0 + ii];
    }
    if (t < 192) {
        int d = t >> 6, ii = t & 63;
        lp[0][d][ii] = x[(i0 + ii)*3 + d] * SQRT_LOG2E;
        lp[1][d][ii] = y[(j0 + ii)*3 + d] * SQRT_LOG2E;
    }
    __syncthreads();

    // d2[ii][jj] = log2(e) * ||x_i - y_j||^2   (positive; negated at use)
    float d2[4][4];
    #pragma unroll
    for (int ii = 0; ii < 4; ++ii) {
        float xi0 = lp[0][0][ty*4+ii];
        float xi1 = lp[0][1][ty*4+ii];
        float xi2 = lp[0][2][ty*4+ii];
        #pragma unroll
        for (int jj = 0; jj < 4; ++jj) {
            float dx = xi0 - lp[1][0][tx*4+jj];
            float dy = xi1 - lp[1][1][tx*4+jj];
            float dz = xi2 - lp[1][2][tx*4+jj];
            d2[ii][jj] = fmaf(dx, dx, fmaf(dy, dy, dz*dz));
        }
    }

    float acc[4][4] = {};
    #pragma unroll
    for (int q = 0; q < QQ; ++q) {
        float4 caiv = *(const float4*)&lf[0][0][q][ty*4];
        float4 saiv = *(const float4*)&lf[0][1][q][ty*4];
        float4 s2iv = *(const float4*)&lf[0][2][q][ty*4];
        float4 cajv = *(const float4*)&lf[1][0][q][tx*4];
        float4 sajv = *(const float4*)&lf[1][1][q][tx*4];
        float4 s2jv = *(const float4*)&lf[1][2][q][tx*4];
        float cai[4] = {caiv.x, caiv.y, caiv.z, caiv.w};
        float sai[4] = {saiv.x, saiv.y, saiv.z, saiv.w};
        float s2i[4] = {s2iv.x, s2iv.y, s2iv.z, s2iv.w};
        float caj[4] = {cajv.x, cajv.y, cajv.z, cajv.w};
        float saj[4] = {sajv.x, sajv.y, sajv.z, sajv.w};
        float s2j[4] = {s2jv.x, s2jv.y, s2jv.z, s2jv.w};
        #pragma unroll
        for (int ii = 0; ii < 4; ++ii) {
            #pragma unroll
            for (int jj = 0; jj < 4; ++jj) {
                float s2  = s2i[ii] + s2j[jj];
                float inv = __builtin_amdgcn_rcpf(s2);
                float e   = exp2_fast(-d2[ii][jj] * inv);
                float ct  = fmaf(cai[ii], caj[jj], sai[ii] * saj[jj]);
                acc[ii][jj] = fmaf(inv * e, ct, acc[ii][jj]);
            }
        }
    }

    #pragma unroll
    for (int ii = 0; ii < 4; ++ii) {
        int i = i0 + ty*4 + ii;
        float4 o = make_float4(acc[ii][0], acc[ii][1], acc[ii][2], acc[ii][3]);
        *(float4*)&K[(size_t)i * NPTS + j0 + tx*4] = o;
    }
}

extern "C" void kernel_launch(void* const* d_in, const int* in_sizes, int n_in,
                              void* d_out, int out_size, void* d_ws, size_t ws_size,
                              hipStream_t stream) {
    const float* x  = (const float*)d_in[0];
    const float* y  = (const float*)d_in[1];
    const float* W1 = (const float*)d_in[2];
    const float* b1 = (const float*)d_in[3];
    const float* Ww = (const float*)d_in[4];
    const float* bw = (const float*)d_in[5];
    const float* Wf = (const float*)d_in[6];
    const float* bf = (const float*)d_in[7];
    const float* Ws = (const float*)d_in[8];
    const float* bs = (const float*)d_in[9];
    float* K = (float*)d_out;

    float* FX = (float*)d_ws;                      // 3*8*2048 floats = 192 KiB
    float* FY = FX + 3 * FSTRIDE;                  // another 192 KiB

    feat_kernel<<<128, 256, 0, stream>>>(x, y, W1, b1, Ww, bw, Wf, bf, Ws, bs, FX, FY);

    dim3 grid(NPTS/64, NPTS/64);
    pair_kernel<<<grid, 256, 0, stream>>>(x, y, FX, FY, K);
}

// Round 4
// 23.603 us; speedup vs baseline: 3.9898x; 1.1443x over previous
//
#include <hip/hip_runtime.h>
#include <math.h>

#define NPTS 2048
#define QQ 8
#define LAT 64
#define LOG2E 1.4426950408889634f
#define SQRT_LOG2E 1.2011224087864498f
#define LN2 0.6931471805599453f

typedef float v2f __attribute__((ext_vector_type(2)));

// Feature buffer layout (per side): [3 feats][QQ][n]
//   feat 0: ca = a * cos(2*pi*phase)     where a = w * 2^(1/4) * sqrt(s)
//   feat 1: sa = a * sin(2*pi*phase)
//   feat 2: s2 = s*s
#define FSTRIDE (QQ * NPTS)

__device__ __forceinline__ float exp2_fast(float v) { return __builtin_amdgcn_exp2f(v); }
__device__ __forceinline__ float log2_fast(float v) { return __builtin_amdgcn_logf(v); }

__device__ __forceinline__ float softplus_f(float v) {
    // log1p(exp(v)) = max(v,0) + ln2 * log2(1 + 2^(-|v|*log2e))
    return fmaxf(v, 0.f) + LN2 * log2_fast(1.f + exp2_fast(-fabsf(v) * LOG2E));
}

// One thread per (point, q). Both sides in one launch.
// Block: 128 threads = 16 points x 8 q. Grid: 256 blocks (0..127 -> x, 128..255 -> y).
__global__ __launch_bounds__(128) void feat_kernel(
    const float* __restrict__ x, const float* __restrict__ y,
    const float* __restrict__ W1, const float* __restrict__ b1,
    const float* __restrict__ Ww, const float* __restrict__ bw,
    const float* __restrict__ Wf, const float* __restrict__ bf,
    const float* __restrict__ Ws, const float* __restrict__ bs,
    float* __restrict__ FX, float* __restrict__ FY)
{
    __shared__ float4 lw1[LAT];      // W1 row + b1, 1 KiB
    __shared__ float  hw[LAT][40];   // [l][head*8 + q], 10 KiB

    const int t = threadIdx.x;
    if (t < LAT) lw1[t] = make_float4(W1[t*3+0], W1[t*3+1], W1[t*3+2], b1[t]);
    #pragma unroll
    for (int j = 0; j < 4; ++j) { int e = t + j*128; int q = e>>6, l = e&63; hw[l][q]   = Ww[e]; }
    #pragma unroll
    for (int j = 0; j < 4; ++j) { int e = t + j*128; int q = e>>6, l = e&63; hw[l][8+q] = Ws[e]; }
    #pragma unroll
    for (int j = 0; j < 12; ++j) {
        int e = t + j*128; int r = e>>6, l = e&63;
        int q = r/3, d = r - 3*q;
        hw[l][(2+d)*8 + q] = Wf[e];
    }
    __syncthreads();

    const int side = blockIdx.x >> 7;                       // 0: x, 1: y
    const int i = ((blockIdx.x & 127) << 4) + (t & 15);     // point index
    const int q = t >> 4;
    const float* P = side ? y : x;
    float* F = side ? FY : FX;

    const float p0 = P[i*3+0], p1 = P[i*3+1], p2 = P[i*3+2];
    float w  = bw[q],     s  = bs[q];
    float f0 = bf[q*3+0], f1 = bf[q*3+1], f2 = bf[q*3+2];
    const float lam = 1.0507009873554805f, lamalf = 1.7580993408473766f;

    #pragma unroll
    for (int l = 0; l < LAT; ++l) {
        float4 wr = lw1[l];
        float v = fmaf(wr.x, p0, fmaf(wr.y, p1, fmaf(wr.z, p2, wr.w)));
        float e = exp2_fast(v * LOG2E);
        float h = v > 0.f ? lam * v : lamalf * (e - 1.f);
        w  = fmaf(hw[l][q],      h, w);
        s  = fmaf(hw[l][8+q],    h, s);
        f0 = fmaf(hw[l][16+q],   h, f0);
        f1 = fmaf(hw[l][24+q],   h, f1);
        f2 = fmaf(hw[l][32+q],   h, f2);
    }
    w  = softplus_f(w);
    s  = softplus_f(s);
    f0 = softplus_f(f0);
    f1 = softplus_f(f1);
    f2 = softplus_f(f2);
    float phase = f0*p0 + f1*p1 + f2*p2;
    // sin(2*pi*phase) via HW sin (operates in revolutions): exact after fract.
    float fr = phase - floorf(phase);
    float sn = __builtin_amdgcn_sinf(fr);
    float cs = __builtin_amdgcn_cosf(fr);
    float a  = w * 1.1892071150027210f * sqrtf(s);
    F[0*FSTRIDE + q*NPTS + i] = a * cs;
    F[1*FSTRIDE + q*NPTS + i] = a * sn;
    F[2*FSTRIDE + q*NPTS + i] = s * s;
}

__global__ __launch_bounds__(256, 4) void pair_kernel(
    const float* __restrict__ x, const float* __restrict__ y,
    const float* __restrict__ FX, const float* __restrict__ FY,
    float* __restrict__ K)
{
    __shared__ float lf[2][3][QQ][64];   // [side][feat][q][pt] = 12 KiB
    __shared__ float lp[2][3][64];       // positions (pre-scaled), 1.5 KiB

    const int t  = threadIdx.x;
    const int tx = t & 15, ty = t >> 4;
    const int i0 = blockIdx.y * 64, j0 = blockIdx.x * 64;

    // Stage 3 feats x 2 sides x 512 floats = 6 elems/thread.
    #pragma unroll
    for (int k = 0; k < 6; ++k) {
        int idx = t + k * 256;               // 0..1535
        int f = idx >> 9, q = (idx >> 6) & 7, ii = idx & 63;
        lf[0][f][q][ii] = FX[f*FSTRIDE + q*NPTS + i0 + ii];
        lf[1][f][q][ii] = FY[f*FSTRIDE + q*NPTS + j0 + ii];
    }
    if (t < 192) {
        int d = t >> 6, ii = t & 63;
        lp[0][d][ii] = x[(i0 + ii)*3 + d] * SQRT_LOG2E;
        lp[1][d][ii] = y[(j0 + ii)*3 + d] * SQRT_LOG2E;
    }
    __syncthreads();

    // d2[ii][jp] = log2(e) * ||x_i - y_j||^2, j packed in pairs
    const v2f* yp0 = (const v2f*)&lp[1][0][tx*4];
    const v2f* yp1 = (const v2f*)&lp[1][1][tx*4];
    const v2f* yp2 = (const v2f*)&lp[1][2][tx*4];
    v2f d2[4][2];
    #pragma unroll
    for (int ii = 0; ii < 4; ++ii) {
        float xi0 = lp[0][0][ty*4+ii];
        float xi1 = lp[0][1][ty*4+ii];
        float xi2 = lp[0][2][ty*4+ii];
        #pragma unroll
        for (int jp = 0; jp < 2; ++jp) {
            v2f dx = xi0 - yp0[jp];
            v2f dy = xi1 - yp1[jp];
            v2f dz = xi2 - yp2[jp];
            d2[ii][jp] = dx*dx + dy*dy + dz*dz;
        }
    }

    v2f acc[4][2] = {};
    #pragma unroll 1
    for (int q = 0; q < QQ; ++q) {
        float4 caiv = *(const float4*)&lf[0][0][q][ty*4];
        float4 saiv = *(const float4*)&lf[0][1][q][ty*4];
        float4 s2iv = *(const float4*)&lf[0][2][q][ty*4];
        float4 cajv = *(const float4*)&lf[1][0][q][tx*4];
        float4 sajv = *(const float4*)&lf[1][1][q][tx*4];
        float4 s2jv = *(const float4*)&lf[1][2][q][tx*4];
        float cai[4] = {caiv.x, caiv.y, caiv.z, caiv.w};
        float sai[4] = {saiv.x, saiv.y, saiv.z, saiv.w};
        float s2i[4] = {s2iv.x, s2iv.y, s2iv.z, s2iv.w};
        v2f caj[2] = {{cajv.x, cajv.y}, {cajv.z, cajv.w}};
        v2f saj[2] = {{sajv.x, sajv.y}, {sajv.z, sajv.w}};
        v2f s2j[2] = {{s2jv.x, s2jv.y}, {s2jv.z, s2jv.w}};
        #pragma unroll
        for (int ii = 0; ii < 4; ++ii) {
            #pragma unroll
            for (int jp = 0; jp < 2; ++jp) {
                v2f s2  = s2i[ii] + s2j[jp];
                v2f inv = { __builtin_amdgcn_rcpf(s2.x), __builtin_amdgcn_rcpf(s2.y) };
                v2f tt  = -d2[ii][jp] * inv;
                v2f e   = { exp2_fast(tt.x), exp2_fast(tt.y) };
                v2f ct  = cai[ii]*caj[jp] + sai[ii]*saj[jp];
                acc[ii][jp] += (inv * e) * ct;
            }
        }
    }

    #pragma unroll
    for (int ii = 0; ii < 4; ++ii) {
        int i = i0 + ty*4 + ii;
        float4 o = make_float4(acc[ii][0].x, acc[ii][0].y, acc[ii][1].x, acc[ii][1].y);
        *(float4*)&K[(size_t)i * NPTS + j0 + tx*4] = o;
    }
}

extern "C" void kernel_launch(void* const* d_in, const int* in_sizes, int n_in,
                              void* d_out, int out_size, void* d_ws, size_t ws_size,
                              hipStream_t stream) {
    const float* x  = (const float*)d_in[0];
    const float* y  = (const float*)d_in[1];
    const float* W1 = (const float*)d_in[2];
    const float* b1 = (const float*)d_in[3];
    const float* Ww = (const float*)d_in[4];
    const float* bw = (const float*)d_in[5];
    const float* Wf = (const float*)d_in[6];
    const float* bf = (const float*)d_in[7];
    const float* Ws = (const float*)d_in[8];
    const float* bs = (const float*)d_in[9];
    float* K = (float*)d_out;

    float* FX = (float*)d_ws;                      // 3*8*2048 floats = 192 KiB
    float* FY = FX + 3 * FSTRIDE;                  // another 192 KiB

    feat_kernel<<<256, 128, 0, stream>>>(x, y, W1, b1, Ww, bw, Wf, bf, Ws, bs, FX, FY);

    dim3 grid(NPTS/64, NPTS/64);
    pair_kernel<<<grid, 256, 0, stream>>>(x, y, FX, FY, K);
}